// Round 7
// baseline (427.438 us; speedup 1.0000x reference)
//
#include <hip/hip_runtime.h>
#include <stdint.h>

#define Bdim 2
#define Tdim 2048
#define Cdim 2048
#define Hdim 16
#define HKVdim 4
#define KVdim 512   // HKV*D
#define KT 32       // attn k-tile rows

typedef __attribute__((ext_vector_type(8))) short bf16x8;
typedef __attribute__((ext_vector_type(4))) float f32x4;

#define GLOAD16(gp, lp) __builtin_amdgcn_global_load_lds( \
    (const __attribute__((address_space(1))) void*)(gp),  \
    (__attribute__((address_space(3))) void*)(lp), 16, 0, 0)
#define WAITV(N) asm volatile("s_waitcnt vmcnt(" #N ")" ::: "memory")
#define WAITL0() asm volatile("s_waitcnt lgkmcnt(0)" ::: "memory")

__device__ __forceinline__ unsigned short f2bf(float f) {
  union { float f; unsigned u; } a; a.f = f;
  unsigned u = a.u + 0x7FFFu + ((a.u >> 16) & 1u);   // RNE
  return (unsigned short)(u >> 16);
}
__device__ __forceinline__ float bf2f(unsigned short h) {
  union { float f; unsigned u; } a; a.u = ((unsigned)h) << 16;
  return a.f;
}

// ---------------- split x into bf16 hi/lo ----------------
__global__ void split_x_kernel(const float* __restrict__ x, unsigned short* __restrict__ hi,
                               unsigned short* __restrict__ lo, int n) {
  int i = blockIdx.x * blockDim.x + threadIdx.x;
  int stride = gridDim.x * blockDim.x;
  for (; i < n; i += stride) {
    float f = x[i];
    unsigned short hb = f2bf(f);
    hi[i] = hb;
    lo[i] = f2bf(f - bf2f(hb));
  }
}

// ---------------- transpose (K,N) fp32 -> (N,K) bf16 hi (+lo) ----------------
__global__ void transpose_split_kernel(const float* __restrict__ in, unsigned short* __restrict__ hi,
                                       unsigned short* __restrict__ lo, int K, int N) {
  __shared__ float tile[32][33];
  int k0 = blockIdx.x * 32, n0 = blockIdx.y * 32;
  int tx = threadIdx.x, ty = threadIdx.y;
#pragma unroll
  for (int i = 0; i < 32; i += 8)
    tile[ty + i][tx] = in[(size_t)(k0 + ty + i) * N + n0 + tx];
  __syncthreads();
#pragma unroll
  for (int i = 0; i < 32; i += 8) {
    float f = tile[tx][ty + i];
    size_t o = (size_t)(n0 + ty + i) * K + k0 + tx;
    unsigned short hb = f2bf(f);
    hi[o] = hb;
    if (lo) lo[o] = f2bf(f - bf2f(hb));
  }
}

// ---------------- counted-vmcnt pipelined QKV GEMM (K-concat split-3) --------------
// BM=128, BN=256, BK=32, 8 waves (2M x 4N), 3 LDS buffers, 2 blocks/CU.
// grid 384: bid<256 q (bm=bid>>3,bn=bid&7, nk=192); <320 k (nk=192); else v (nk=64).
// K-concat regions for q/k: kt>>6 = 0:(xhi,Wh) 1:(xlo,Wh) 2:(xhi,Wl).
// LDS per buf: A 128x64B (8KB) + B 256x64B (16KB); source-XOR swizzle (row&3)<<4.
__global__ __launch_bounds__(512, 4) void qkv8_kernel(
    const unsigned short* __restrict__ xhi, const unsigned short* __restrict__ xlo,
    const unsigned short* __restrict__ WqThi, const unsigned short* __restrict__ WqTlo,
    const unsigned short* __restrict__ WkThi, const unsigned short* __restrict__ WkTlo,
    const unsigned short* __restrict__ WvThi,
    const float* __restrict__ cs, const float* __restrict__ sn,
    unsigned short* __restrict__ qhi, unsigned short* __restrict__ qlo,
    unsigned short* __restrict__ khi, unsigned short* __restrict__ klo,
    unsigned short* __restrict__ vun)
{
  __shared__ char sL[3][24576];
  int tid = threadIdx.x, wid = tid >> 6, lane = tid & 63;
  int bid = blockIdx.x;
  int mode, bm, bn;
  if (bid < 256)      { mode = 0; bm = bid >> 3; bn = bid & 7; }
  else if (bid < 320) { int i = bid - 256; mode = 1; bm = i >> 1; bn = i & 1; }
  else                { int i = bid - 320; mode = 2; bm = i >> 1; bn = i & 1; }
  const unsigned short *Bhp, *Blp = WqTlo;
  if (mode == 0)      { Bhp = WqThi; Blp = WqTlo; }
  else if (mode == 1) { Bhp = WkThi; Blp = WkTlo; }
  else                { Bhp = WvThi; }
  int nk = (mode == 2) ? 64 : 192;

  const char* xh = (const char*)xhi;
  const char* xl = (const char*)xlo;
  const char* Bh = (const char*)Bhp;
  const char* Bl = (const char*)Blp;
  size_t arow0 = (size_t)bm * 128;
  size_t brow0 = (size_t)bn * 256;

  int wrow = (wid >> 2) & 1, wcol = wid & 3;
  int ln15 = lane & 15, j16 = (lane >> 4) * 16;

  f32x4 acc[4][4];
#pragma unroll
  for (int rf = 0; rf < 4; ++rf)
#pragma unroll
    for (int cf = 0; cf < 4; ++cf)
      acc[rf][cf] = f32x4{0.f, 0.f, 0.f, 0.f};

  auto stage = [&](int buf, int kt) {
    int reg = kt >> 6;
    int kk2 = (kt & 63) * 64;                 // k byte offset
    const char* As = (reg == 1) ? xl : xh;
    const char* Bs = (reg == 2) ? Bl : Bh;
    {
      int o = tid * 16; int row = o >> 6; int c = (o & 63) ^ ((row & 3) << 4);
      GLOAD16(As + (arow0 + row) * 4096 + kk2 + c, &sL[buf][o]);
    }
#pragma unroll
    for (int i = 0; i < 2; ++i) {
      int o = (i * 512 + tid) * 16; int row = o >> 6; int c = (o & 63) ^ ((row & 3) << 4);
      GLOAD16(Bs + (brow0 + row) * 4096 + kk2 + c, &sL[buf][8192 + o]);
    }
  };

  stage(0, 0); stage(1, 1); stage(2, 2);
  WAITV(6);                                  // tile 0 landed (this wave's 3 loads)
  __builtin_amdgcn_s_barrier();

  int cb = 0;
  for (int kt = 0; kt < nk; ++kt) {
    bf16x8 a[4], b[4];
    const char* base = sL[cb];
#pragma unroll
    for (int rf = 0; rf < 4; ++rf) {
      int r = wrow * 64 + rf * 16 + ln15;
      a[rf] = *(const bf16x8*)(base + r * 64 + (j16 ^ ((r & 3) << 4)));
    }
#pragma unroll
    for (int cf = 0; cf < 4; ++cf) {
      int r = wcol * 64 + cf * 16 + ln15;
      b[cf] = *(const bf16x8*)(base + 8192 + r * 64 + (j16 ^ ((r & 3) << 4)));
    }
    WAITL0();                                // reads in regs before crossing barrier
    __builtin_amdgcn_sched_barrier(0);
    __builtin_amdgcn_s_barrier();            // all waves done reading cb
    if (kt + 3 < nk)      { stage(cb, kt + 3); WAITV(6); }  // kt+1 landed; 2-3 tiles stay in flight
    else if (kt + 2 < nk) { WAITV(3); }
    else                  { WAITV(0); }
    __builtin_amdgcn_s_setprio(1);
#pragma unroll
    for (int rf = 0; rf < 4; ++rf)
#pragma unroll
      for (int cf = 0; cf < 4; ++cf)
        acc[rf][cf] = __builtin_amdgcn_mfma_f32_16x16x32_bf16(a[rf], b[cf], acc[rf][cf], 0, 0, 0);
    __builtin_amdgcn_s_setprio(0);
    __builtin_amdgcn_s_barrier();            // all waves confirmed next tile resident
    cb = (cb == 2) ? 0 : cb + 1;
  }

  // epilogue
  if (mode <= 1) {
    int nh = (mode == 0) ? Hdim : HKVdim;
    unsigned short* oph = (mode == 0) ? qhi : khi;
    unsigned short* opl = (mode == 0) ? qlo : klo;
#pragma unroll
    for (int rf = 0; rf < 4; ++rf)
#pragma unroll
      for (int rr = 0; rr < 4; ++rr) {
        int rowl = wrow * 64 + rf * 16 + (lane >> 4) * 4 + rr;
        int grow = bm * 128 + rowl;
        int t = grow & (Tdim - 1), bb = grow >> 11;
#pragma unroll
        for (int cf = 0; cf < 4; ++cf) {
          int ncol = wcol * 64 + cf * 16 + ln15;
          int h = bn * 2 + (ncol >> 7);
          int d = ncol & 127;
          float o;
          if ((wcol & 1) == 0) {             // d < 64: RoPE; partner at cf+-2
            float c = cs[t * 64 + d], s = sn[t * 64 + d];
            o = (cf < 2) ? (acc[rf][cf][rr] * c - acc[rf][cf + 2][rr] * s)
                         : (acc[rf][cf][rr] * c + acc[rf][cf - 2][rr] * s);
          } else o = acc[rf][cf][rr];
          size_t ob = (((size_t)(bb * nh + h)) * Tdim + t) * 128 + d;
          unsigned short hb = f2bf(o);
          oph[ob] = hb;
          opl[ob] = f2bf(o - bf2f(hb));
        }
      }
  } else {
#pragma unroll
    for (int rf = 0; rf < 4; ++rf)
#pragma unroll
      for (int rr = 0; rr < 4; ++rr) {
        int rowl = wrow * 64 + rf * 16 + (lane >> 4) * 4 + rr;
        int grow = bm * 128 + rowl;
        int t = grow & (Tdim - 1), bb = grow >> 11;
#pragma unroll
        for (int cf = 0; cf < 4; ++cf) {
          int ncol = wcol * 64 + cf * 16 + ln15;
          int g = bn * 2 + (ncol >> 7);
          int d = ncol & 127;
          vun[(((size_t)(bb * HKVdim + g)) * Tdim + t) * 128 + d] = f2bf(acc[rf][cf][rr]);
        }
      }
  }
}

// ---------------- counted-vmcnt pipelined Wo GEMM ----------------
// Same skeleton, plain bf16, K=2048 (nk=64), out fp32. grid 256 (bm 0..31, bn 0..7).
__global__ __launch_bounds__(512, 4) void wo8_kernel(
    const unsigned short* __restrict__ A, const unsigned short* __restrict__ Bt,
    float* __restrict__ C)
{
  __shared__ char sL[3][24576];
  int tid = threadIdx.x, wid = tid >> 6, lane = tid & 63;
  int bm = blockIdx.x >> 3, bn = blockIdx.x & 7;
  const char* As = (const char*)A;
  const char* Bs = (const char*)Bt;
  size_t arow0 = (size_t)bm * 128;
  size_t brow0 = (size_t)bn * 256;
  int wrow = (wid >> 2) & 1, wcol = wid & 3;
  int ln15 = lane & 15, j16 = (lane >> 4) * 16;
  const int nk = 64;

  f32x4 acc[4][4];
#pragma unroll
  for (int rf = 0; rf < 4; ++rf)
#pragma unroll
    for (int cf = 0; cf < 4; ++cf)
      acc[rf][cf] = f32x4{0.f, 0.f, 0.f, 0.f};

  auto stage = [&](int buf, int kt) {
    int kk2 = kt * 64;
    {
      int o = tid * 16; int row = o >> 6; int c = (o & 63) ^ ((row & 3) << 4);
      GLOAD16(As + (arow0 + row) * 4096 + kk2 + c, &sL[buf][o]);
    }
#pragma unroll
    for (int i = 0; i < 2; ++i) {
      int o = (i * 512 + tid) * 16; int row = o >> 6; int c = (o & 63) ^ ((row & 3) << 4);
      GLOAD16(Bs + (brow0 + row) * 4096 + kk2 + c, &sL[buf][8192 + o]);
    }
  };

  stage(0, 0); stage(1, 1); stage(2, 2);
  WAITV(6);
  __builtin_amdgcn_s_barrier();

  int cb = 0;
  for (int kt = 0; kt < nk; ++kt) {
    bf16x8 a[4], b[4];
    const char* base = sL[cb];
#pragma unroll
    for (int rf = 0; rf < 4; ++rf) {
      int r = wrow * 64 + rf * 16 + ln15;
      a[rf] = *(const bf16x8*)(base + r * 64 + (j16 ^ ((r & 3) << 4)));
    }
#pragma unroll
    for (int cf = 0; cf < 4; ++cf) {
      int r = wcol * 64 + cf * 16 + ln15;
      b[cf] = *(const bf16x8*)(base + 8192 + r * 64 + (j16 ^ ((r & 3) << 4)));
    }
    WAITL0();
    __builtin_amdgcn_sched_barrier(0);
    __builtin_amdgcn_s_barrier();
    if (kt + 3 < nk)      { stage(cb, kt + 3); WAITV(6); }
    else if (kt + 2 < nk) { WAITV(3); }
    else                  { WAITV(0); }
    __builtin_amdgcn_s_setprio(1);
#pragma unroll
    for (int rf = 0; rf < 4; ++rf)
#pragma unroll
      for (int cf = 0; cf < 4; ++cf)
        acc[rf][cf] = __builtin_amdgcn_mfma_f32_16x16x32_bf16(a[rf], b[cf], acc[rf][cf], 0, 0, 0);
    __builtin_amdgcn_s_setprio(0);
    __builtin_amdgcn_s_barrier();
    cb = (cb == 2) ? 0 : cb + 1;
  }

#pragma unroll
  for (int rf = 0; rf < 4; ++rf)
#pragma unroll
    for (int rr = 0; rr < 4; ++rr) {
      int grow = bm * 128 + wrow * 64 + rf * 16 + (lane >> 4) * 4 + rr;
#pragma unroll
      for (int cf = 0; cf < 4; ++cf) {
        int gcol = bn * 256 + wcol * 64 + cf * 16 + ln15;
        C[(size_t)grow * Cdim + gcol] = acc[rf][cf][rr];
      }
    }
}

// ---------------- v transpose: (b,g,t,d) bf16 -> (b,g,d,t) bf16 ----------------
__global__ void transpose_v_bf16_kernel(const unsigned short* __restrict__ vsrc,
                                        unsigned short* __restrict__ vt) {
  __shared__ unsigned short tile[32][33];
  int bg = blockIdx.x;
  int t0 = blockIdx.y * 32, d0 = blockIdx.z * 32;
  int tx = threadIdx.x, ty = threadIdx.y;
#pragma unroll
  for (int i = 0; i < 32; i += 8)
    tile[ty + i][tx] = vsrc[((size_t)bg * Tdim + t0 + ty + i) * 128 + d0 + tx];
  __syncthreads();
#pragma unroll
  for (int i = 0; i < 32; i += 8)
    vt[((size_t)(bg * 128 + d0 + ty + i)) * Tdim + t0 + tx] = tile[tx][ty + i];
}

// ---------------- fused causal GQA attention with post-softmax gate ----------------
// Fixed-M softmax (M=8, exp2 with folded scale*log2e). Two-pass, pass-B block skip.
__global__ __launch_bounds__(512, 4) void attn_kernel(
    const unsigned short* __restrict__ qhi, const unsigned short* __restrict__ qlo,
    const unsigned short* __restrict__ khi, const unsigned short* __restrict__ klo,
    const unsigned short* __restrict__ vt, const float* __restrict__ gate,
    unsigned short* __restrict__ y)
{
  __shared__ alignas(16) unsigned short sKh[2][KT * 128];
  __shared__ alignas(16) unsigned short sKl[2][KT * 128];
  __shared__ alignas(16) unsigned short sV[2][128 * KT];
  __shared__ alignas(16) unsigned short sP[8][16 * 40];
  __shared__ float sBM[8][64];

  int qb = (gridDim.x - 1) - blockIdx.x;     // heavy blocks first
  int bh = blockIdx.y;
  int b = bh >> 4, h = bh & 15;
  int g = h >> 2;
  int t0 = qb * 128;
  int tid = threadIdx.x, wid = tid >> 6, lane = tid & 63;
  int ln15 = lane & 15, j16 = (lane >> 4) * 16, ro4 = (lane >> 4) * 4;
  const float cs2 = 0.08838834764831845f * 1.4426950408889634f;  // scale*log2(e)
  const float M2  = 8.0f * 1.4426950408889634f;

  const unsigned short* kh_base = khi + (((size_t)b * HKVdim + g) * Tdim) * 128;
  const unsigned short* kl_base = klo + (((size_t)b * HKVdim + g) * Tdim) * 128;
  const unsigned short* v_base  = vt  + (((size_t)b * HKVdim + g) * 128) * (size_t)Tdim;

  bf16x8 aqh[4], aql[4];
  {
    size_t qoff = ((((size_t)b * Hdim + h) * Tdim) + t0 + wid * 16 + ln15) * 128 + (lane >> 4) * 8;
#pragma unroll
    for (int kf = 0; kf < 4; ++kf) {
      aqh[kf] = *(const bf16x8*)(qhi + qoff + kf * 32);
      aql[kf] = *(const bf16x8*)(qlo + qoff + kf * 32);
    }
  }
  float thr = 1.f / (1.f + expf(-gate[h]));

  int nkb = (qb + 1) * 4;
  int tq_lo = t0 + wid * 16;

  auto stageK = [&](int buf, int kb) {
    int o = wid * 1024 + lane * 16;
    int row = o >> 8;
    int col = (o & 255) ^ ((row & 7) << 4);
    size_t goff = ((size_t)(kb * KT + row)) * 256 + col;
    GLOAD16((const char*)kh_base + goff, (char*)sKh[buf] + wid * 1024);
    GLOAD16((const char*)kl_base + goff, (char*)sKl[buf] + wid * 1024);
  };
  auto stageV = [&](int buf, int kb) {
    int o = wid * 1024 + lane * 16;
    int row = o >> 6;
    int col = (o & 63) ^ (((row ^ (row >> 2)) & 3) << 4);
    size_t goff = (size_t)row * (Tdim * 2) + (size_t)kb * 64 + col;
    GLOAD16((const char*)v_base + goff, (char*)sV[buf] + wid * 1024);
  };
  auto qk = [&](int buf, f32x4* s) {
    __builtin_amdgcn_s_setprio(1);
#pragma unroll
    for (int nf = 0; nf < 2; ++nf) {
      f32x4 a = {0.f, 0.f, 0.f, 0.f};
      int krow = nf * 16 + ln15;
      int sw = (krow & 7) << 4;
#pragma unroll
      for (int kf = 0; kf < 4; ++kf) {
        int boff = (kf * 64 + j16) ^ sw;
        bf16x8 bh_ = *(const bf16x8*)((const char*)sKh[buf] + krow * 256 + boff);
        bf16x8 bl_ = *(const bf16x8*)((const char*)sKl[buf] + krow * 256 + boff);
        a = __builtin_amdgcn_mfma_f32_16x16x32_bf16(aqh[kf], bh_, a, 0, 0, 0);
        a = __builtin_amdgcn_mfma_f32_16x16x32_bf16(aql[kf], bh_, a, 0, 0, 0);
        a = __builtin_amdgcn_mfma_f32_16x16x32_bf16(aqh[kf], bl_, a, 0, 0, 0);
      }
      s[nf] = a;
    }
    __builtin_amdgcn_s_setprio(0);
  };

  float lloc[4];
#pragma unroll
  for (int r = 0; r < 4; ++r) lloc[r] = 0.f;

  // ---- PASS A ----
  stageK(0, 0);
  __syncthreads();
  for (int kb = 0; kb < nkb; ++kb) {
    int buf = kb & 1;
    if (kb + 1 < nkb) stageK(buf ^ 1, kb + 1);
    if (kb * KT <= tq_lo + 15) {
      f32x4 s[2];
      qk(buf, s);
      float wmax = -1e30f;
      bool full = (kb * KT + KT - 1) <= tq_lo;
      if (full) {
#pragma unroll
        for (int nf = 0; nf < 2; ++nf)
#pragma unroll
          for (int r = 0; r < 4; ++r) {
            float v = s[nf][r] * cs2;
            wmax = fmaxf(wmax, v);
            lloc[r] += __builtin_exp2f(v - M2);
          }
      } else {
#pragma unroll
        for (int nf = 0; nf < 2; ++nf) {
          int tk = kb * KT + nf * 16 + ln15;
#pragma unroll
          for (int r = 0; r < 4; ++r) {
            int tq = tq_lo + ro4 + r;
            float v = (tk <= tq) ? s[nf][r] * cs2 : -1e30f;
            wmax = fmaxf(wmax, v);
            lloc[r] += __builtin_exp2f(v - M2);
          }
        }
      }
#pragma unroll
      for (int off = 1; off < 64; off <<= 1)
        wmax = fmaxf(wmax, __shfl_xor(wmax, off));
      if (lane == 0) sBM[wid][kb] = wmax;
    }
    __syncthreads();
  }

  float lrow[4], lgate2[4];
#pragma unroll
  for (int r = 0; r < 4; ++r) {
    float l = lloc[r];
#pragma unroll
    for (int off = 1; off < 16; off <<= 1) l += __shfl_xor(l, off);
    lrow[r] = l;
    lgate2[r] = __log2f(thr * l) + M2;
  }
  float lgmin = fminf(fminf(lgate2[0], lgate2[1]), fminf(lgate2[2], lgate2[3]));
  lgmin = fminf(lgmin, __shfl_xor(lgmin, 16));
  lgmin = fminf(lgmin, __shfl_xor(lgmin, 32));

  // ---- PASS B ----
  f32x4 yacc[8];
#pragma unroll
  for (int n = 0; n < 8; ++n) yacc[n] = f32x4{0.f, 0.f, 0.f, 0.f};

  stageK(0, 0);
  stageV(0, 0);
  __syncthreads();
  for (int kb = 0; kb < nkb; ++kb) {
    int buf = kb & 1;
    if (kb + 1 < nkb) { stageK(buf ^ 1, kb + 1); stageV(buf ^ 1, kb + 1); }
    if (kb * KT <= tq_lo + 15 && sBM[wid][kb] >= lgmin) {
      f32x4 s[2];
      qk(buf, s);
      bool anyk = false;
      float pv[2][4];
      bool full = (kb * KT + KT - 1) <= tq_lo;
#pragma unroll
      for (int nf = 0; nf < 2; ++nf) {
        int tk = kb * KT + nf * 16 + ln15;
#pragma unroll
        for (int r = 0; r < 4; ++r) {
          int tq = tq_lo + ro4 + r;
          float v = s[nf][r] * cs2;
          bool keep = (full || tk <= tq) && (v >= lgate2[r]);
          float p = 0.f;
          if (keep) { p = __builtin_exp2f(v - M2); anyk = true; }
          pv[nf][r] = p;
        }
      }
      if (__any(anyk)) {
#pragma unroll
        for (int nf = 0; nf < 2; ++nf)
#pragma unroll
          for (int r = 0; r < 4; ++r)
            sP[wid][(ro4 + r) * 40 + nf * 16 + ln15] = f2bf(pv[nf][r]);
        __builtin_amdgcn_s_setprio(1);
        bf16x8 pa = *(const bf16x8*)&sP[wid][ln15 * 40 + (lane >> 4) * 8];
#pragma unroll
        for (int nf2 = 0; nf2 < 8; ++nf2) {
          int vrow = nf2 * 16 + ln15;
          int vboff = j16 ^ (((vrow ^ (vrow >> 2)) & 3) << 4);
          bf16x8 vb = *(const bf16x8*)((const char*)sV[buf] + vrow * 64 + vboff);
          yacc[nf2] = __builtin_amdgcn_mfma_f32_16x16x32_bf16(pa, vb, yacc[nf2], 0, 0, 0);
        }
        __builtin_amdgcn_s_setprio(0);
      }
    }
    __syncthreads();
  }

#pragma unroll
  for (int r = 0; r < 4; ++r) {
    int tq = t0 + wid * 16 + ro4 + r;
    float invl = 1.f / lrow[r];
    size_t base = ((size_t)(b * Tdim + tq)) * Cdim + h * 128;
#pragma unroll
    for (int nf2 = 0; nf2 < 8; ++nf2)
      y[base + nf2 * 16 + ln15] = f2bf(yacc[nf2][r] * invl);
  }
}

extern "C" void kernel_launch(void* const* d_in, const int* in_sizes, int n_in,
                              void* d_out, int out_size, void* d_ws, size_t ws_size,
                              hipStream_t stream)
{
  (void)in_sizes; (void)n_in; (void)out_size; (void)ws_size;
  const float* x    = (const float*)d_in[0];
  const float* cosT = (const float*)d_in[1];
  const float* sinT = (const float*)d_in[2];
  const float* Wq   = (const float*)d_in[3];
  const float* Wk   = (const float*)d_in[4];
  const float* Wv   = (const float*)d_in[5];
  const float* Wo   = (const float*)d_in[6];
  const float* gate = (const float*)d_in[7];
  float* out = (float*)d_out;

  char* ws = (char*)d_ws;
  size_t off = 0;
  auto alloc = [&](size_t bytes) -> char* {
    char* p = ws + off; off += (bytes + 255) & ~(size_t)255; return p;
  };
  const size_t NX = (size_t)Bdim * Tdim * Cdim;    // 8388608
  const size_t NK = (size_t)Bdim * Tdim * KVdim;   // 2097152

  unsigned short* xhi   = (unsigned short*)alloc(NX * 2);
  unsigned short* xlo   = (unsigned short*)alloc(NX * 2);
  unsigned short* WqThi = (unsigned short*)alloc((size_t)Cdim * Cdim * 2);
  unsigned short* WqTlo = (unsigned short*)alloc((size_t)Cdim * Cdim * 2);
  unsigned short* WkThi = (unsigned short*)alloc((size_t)Cdim * KVdim * 2);
  unsigned short* WkTlo = (unsigned short*)alloc((size_t)Cdim * KVdim * 2);
  unsigned short* WvThi = (unsigned short*)alloc((size_t)Cdim * KVdim * 2);
  unsigned short* WoThi = (unsigned short*)alloc((size_t)Cdim * Cdim * 2);
  unsigned short* qhi   = (unsigned short*)alloc(NX * 2);
  unsigned short* qlo   = (unsigned short*)alloc(NX * 2);
  unsigned short* khi   = (unsigned short*)alloc(NK * 2);
  unsigned short* klo   = (unsigned short*)alloc(NK * 2);
  unsigned short* vun   = (unsigned short*)alloc(NK * 2);
  unsigned short* vtr   = (unsigned short*)alloc(NK * 2);
  unsigned short* yb    = (unsigned short*)alloc(NX * 2);

  dim3 tb(32, 8);
  split_x_kernel<<<2048, 256, 0, stream>>>(x, xhi, xlo, (int)NX);
  transpose_split_kernel<<<dim3(64, 64), tb, 0, stream>>>(Wq, WqThi, WqTlo, Cdim, Cdim);
  transpose_split_kernel<<<dim3(64, 16), tb, 0, stream>>>(Wk, WkThi, WkTlo, Cdim, KVdim);
  transpose_split_kernel<<<dim3(64, 16), tb, 0, stream>>>(Wv, WvThi, nullptr, Cdim, KVdim);
  transpose_split_kernel<<<dim3(64, 64), tb, 0, stream>>>(Wo, WoThi, nullptr, Cdim, Cdim);

  qkv8_kernel<<<384, 512, 0, stream>>>(
      xhi, xlo, WqThi, WqTlo, WkThi, WkTlo, WvThi,
      cosT, sinT, qhi, qlo, khi, klo, vun);
  transpose_v_bf16_kernel<<<dim3(8, 64, 4), tb, 0, stream>>>(vun, vtr);

  attn_kernel<<<dim3(16, 32), 512, 0, stream>>>(qhi, qlo, khi, klo, vtr, gate, yb);

  wo8_kernel<<<256, 512, 0, stream>>>(yb, WoThi, out);
}